// Round 1
// baseline (713.672 us; speedup 1.0000x reference)
//
#include <hip/hip_runtime.h>
#include <stdint.h>

// Problem constants (B=2, H=16, S=2048, D=64)
constexpr int S   = 2048;
constexpr int D   = 64;
constexpr int BH  = 32;      // B*H
constexpr int QT  = 64;      // q rows per block (16 per wave)
constexpr int KT  = 64;      // k rows per tile
constexpr int LDP = 72;      // padded LDS row length in shorts (144 B, 16B multiple)

using short8  = __attribute__((ext_vector_type(8))) short;
using float4v = __attribute__((ext_vector_type(4))) float;

static __device__ __forceinline__ unsigned short f2bf(float f) {
    union { float f; unsigned u; } x; x.f = f;
    unsigned u = x.u;
    u += 0x7fffu + ((u >> 16) & 1u);   // round-to-nearest-even
    return (unsigned short)(u >> 16);
}

// ---------------------------------------------------------------------------
// Pre-kernel A: K bf16 row-major copy (amortizes f32->bf16 over the 64
// re-reads each K row gets from the main kernel). 8 MB into d_ws.
// ---------------------------------------------------------------------------
__global__ __launch_bounds__(256) void cvt_kernel(const float* __restrict__ src,
                                                  unsigned short* __restrict__ dst) {
#pragma unroll
    for (int i = 0; i < 4; ++i) {
        const size_t f4 = (size_t)blockIdx.x * 1024 + i * 256 + threadIdx.x;
        float4v val = ((const float4v*)src)[f4];
        ushort4 pk;
        pk.x = f2bf(val.x);
        pk.y = f2bf(val.y);
        pk.z = f2bf(val.z);
        pk.w = f2bf(val.w);
        ((ushort4*)dst)[f4] = pk;
    }
}

// ---------------------------------------------------------------------------
// Pre-kernel B: Vt[bh][d][k] = bf16(V[bh][k][d])  (8 MB into d_ws)
// ---------------------------------------------------------------------------
__global__ __launch_bounds__(256) void vt_kernel(const float* __restrict__ v,
                                                 unsigned short* __restrict__ vt) {
    __shared__ __align__(16) unsigned short sT[64][LDP];
    const int blk = blockIdx.x;          // 0..1023
    const int bh  = blk >> 5;            // 0..31
    const int k0  = (blk & 31) << 6;     // 0,64,...,1984
    const int t   = threadIdx.x;
    const float* vp = v + ((size_t)bh * S + k0) * D;
#pragma unroll
    for (int i = 0; i < 4; ++i) {
        const int f4 = t + 256 * i;
        float4v val = ((const float4v*)vp)[f4];
        const int e = f4 * 4;
        const int r = e >> 6;
        const int c = e & 63;
        sT[c + 0][r] = f2bf(val.x);
        sT[c + 1][r] = f2bf(val.y);
        sT[c + 2][r] = f2bf(val.z);
        sT[c + 3][r] = f2bf(val.w);
    }
    __syncthreads();
#pragma unroll
    for (int i = 0; i < 2; ++i) {
        const int f    = t + 256 * i;
        const int drow = f >> 3;
        const int kc   = (f & 7) * 8;
        short8 val = *(const short8*)&sT[drow][kc];
        *(short8*)(vt + ((size_t)bh * D + drow) * S + k0 + kc) = val;
    }
}

// ---------------------------------------------------------------------------
// Main fused attention kernel. 256 threads (4 waves), 64 q rows per block.
// Loop 1: QK^T -> exp*mask -> row sums l, unnormalized O (PV via MFMA).
// Loop 2: recompute QK^T, write attn = exp*mask/l via transposed float4 stores.
// 2 barriers per tile (sP is wave-private; same-wave LDS ordering is
// handled by compiler-inserted lgkmcnt waits).
// ---------------------------------------------------------------------------
__global__ __launch_bounds__(256, 4) void attn_kernel(const float* __restrict__ q,
                                                      const unsigned short* __restrict__ kb,
                                                      const int* __restrict__ mask,
                                                      const unsigned short* __restrict__ vt,
                                                      float* __restrict__ out) {
    __shared__ __align__(16) unsigned short sQ[QT][LDP];
    __shared__ __align__(16) unsigned short sK[KT][LDP];
    __shared__ __align__(16) unsigned short sVt[D][LDP];
    __shared__ __align__(16) unsigned short sP[4][16][LDP];   // per-wave P strip

    const int tid  = threadIdx.x;
    const int wave = tid >> 6;
    const int lane = tid & 63;
    const int quad = lane >> 4;
    const int n16  = lane & 15;

    // XCD-contiguous remap: 1024 blocks, 8 XCDs, 128 blocks (4 bh) per XCD.
    // K+Vt working set per XCD = 4 * (256KB + 256KB) = 2 MB < 4 MB L2.
    const int bx0 = blockIdx.x;
    const int bx  = (bx0 & 7) * 128 + (bx0 >> 3);
    const int bh  = bx >> 5;        // 0..31
    const int qt  = bx & 31;
    const int q0  = qt * QT;
    const int b   = bh >> 4;        // batch index (H=16)

    const float* qp = q + ((size_t)bh * S + q0) * D;
    const unsigned short* kp  = kb + (size_t)bh * S * D;
    const unsigned short* vtp = vt + (size_t)bh * D * S;
    const int* mp = mask + b * S;

    // ---- stage sQ (scaled by 1/temperature = 1/8), bf16; once per block ----
    {
        const float4v* src = (const float4v*)qp;
#pragma unroll
        for (int i = 0; i < 4; ++i) {
            const int f4 = tid + 256 * i;
            float4v val = src[f4];
            const int e = f4 * 4;
            const int row = e >> 6, col = e & 63;
            ushort4 pk;
            pk.x = f2bf(val.x * 0.125f);
            pk.y = f2bf(val.y * 0.125f);
            pk.z = f2bf(val.z * 0.125f);
            pk.w = f2bf(val.w * 0.125f);
            *(ushort4*)&sQ[row][col] = pk;
        }
    }
    __syncthreads();

    // Q A-fragments: row = wave*16 + (lane&15), k = c*32 + quad*8 + j
    const short8 aq0 = *(const short8*)&sQ[wave * 16 + n16][quad * 8];
    const short8 aq1 = *(const short8*)&sQ[wave * 16 + n16][32 + quad * 8];

    float4v accO[4];
    const float4v zero4 = {0.f, 0.f, 0.f, 0.f};
#pragma unroll
    for (int nv = 0; nv < 4; ++nv) accO[nv] = zero4;
    float lsum[4] = {0.f, 0.f, 0.f, 0.f};

    // =========================== Loop 1 ===========================
    for (int kt = 0; kt < S / KT; ++kt) {
        const int k0 = kt * KT;
        __syncthreads();   // prior iteration's LDS reads done before restage
        // stage sK (bf16 copy) + sVt (bf16 copy), 4x short8 per thread
        {
            const unsigned short* ks = kp + (size_t)k0 * D;
#pragma unroll
            for (int i = 0; i < 2; ++i) {
                const int f = tid + 256 * i;          // 0..511
                short8 val = *(const short8*)(ks + f * 8);
                *(short8*)&sK[f >> 3][(f & 7) * 8] = val;
            }
#pragma unroll
            for (int i = 0; i < 2; ++i) {
                const int f    = tid + 256 * i;
                const int drow = f >> 3;
                const int kc8  = (f & 7) * 8;
                short8 val = *(const short8*)(vtp + (size_t)drow * S + k0 + kc8);
                *(short8*)&sVt[drow][kc8] = val;
            }
        }
        __syncthreads();

        // QK^T: S-strip 16x64 per wave
        float4v cf[4];
#pragma unroll
        for (int nc = 0; nc < 4; ++nc) cf[nc] = zero4;
        __builtin_amdgcn_s_setprio(1);
#pragma unroll
        for (int c = 0; c < 2; ++c) {
            const short8 a = (c == 0) ? aq0 : aq1;
#pragma unroll
            for (int nc = 0; nc < 4; ++nc) {
                const short8 bfr = *(const short8*)&sK[nc * 16 + n16][c * 32 + quad * 8];
                cf[nc] = __builtin_amdgcn_mfma_f32_16x16x32_bf16(a, bfr, cf[nc], 0, 0, 0);
            }
        }
        __builtin_amdgcn_s_setprio(0);

        // p = exp(s) * mask  (no max subtraction needed: |s| <~ 6)
        float pv_[4][4];
#pragma unroll
        for (int nc = 0; nc < 4; ++nc) {
            const int mvi = mp[k0 + nc * 16 + n16];
#pragma unroll
            for (int r = 0; r < 4; ++r)
                pv_[nc][r] = mvi ? __expf(cf[nc][r]) : 0.f;
        }
        // row sums (reduce across the 16 lanes of each quad)
#pragma unroll
        for (int r = 0; r < 4; ++r) {
            float s = pv_[0][r] + pv_[1][r] + pv_[2][r] + pv_[3][r];
            s += __shfl_xor(s, 1, 64);
            s += __shfl_xor(s, 2, 64);
            s += __shfl_xor(s, 4, 64);
            s += __shfl_xor(s, 8, 64);
            lsum[r] += s;
        }
        // C-layout -> per-wave LDS strip for A-layout reload (wave-private:
        // no barrier needed, compiler inserts lgkmcnt waits)
#pragma unroll
        for (int nc = 0; nc < 4; ++nc)
#pragma unroll
            for (int r = 0; r < 4; ++r)
                sP[wave][quad * 4 + r][nc * 16 + n16] = f2bf(pv_[nc][r]);

        // PV: O += P @ V
        __builtin_amdgcn_s_setprio(1);
#pragma unroll
        for (int kc = 0; kc < 2; ++kc) {
            const short8 ap = *(const short8*)&sP[wave][n16][kc * 32 + quad * 8];
#pragma unroll
            for (int nv = 0; nv < 4; ++nv) {
                const short8 bv = *(const short8*)&sVt[nv * 16 + n16][kc * 32 + quad * 8];
                accO[nv] = __builtin_amdgcn_mfma_f32_16x16x32_bf16(ap, bv, accO[nv], 0, 0, 0);
            }
        }
        __builtin_amdgcn_s_setprio(0);
    }

    // ---- normalize and store O ----
    float linv[4];
#pragma unroll
    for (int r = 0; r < 4; ++r) linv[r] = 1.0f / lsum[r];

    {
        const size_t obase = ((size_t)bh * S + q0 + wave * 16) * D;
#pragma unroll
        for (int nv = 0; nv < 4; ++nv)
#pragma unroll
            for (int r = 0; r < 4; ++r)
                out[obase + (size_t)(quad * 4 + r) * D + nv * 16 + n16] = accO[nv][r] * linv[r];
    }

    // ============== Loop 2: write attn (transposed float4 stores) ==============
    float* attn = out + (size_t)BH * S * D;
    const size_t abase = (size_t)bh * S * S + (size_t)(q0 + wave * 16) * S;
    const int t4 = n16 & 3;   // row within 4x4 transpose group
    const int g4 = n16 >> 2;  // column group (4 floats each)
    for (int kt = 0; kt < S / KT; ++kt) {
        const int k0 = kt * KT;
        __syncthreads();
        {
            const unsigned short* ks = kp + (size_t)k0 * D;
#pragma unroll
            for (int i = 0; i < 2; ++i) {
                const int f = tid + 256 * i;
                short8 val = *(const short8*)(ks + f * 8);
                *(short8*)&sK[f >> 3][(f & 7) * 8] = val;
            }
        }
        __syncthreads();

        float4v cf[4];
#pragma unroll
        for (int nc = 0; nc < 4; ++nc) cf[nc] = zero4;
        __builtin_amdgcn_s_setprio(1);
#pragma unroll
        for (int c = 0; c < 2; ++c) {
            const short8 a = (c == 0) ? aq0 : aq1;
#pragma unroll
            for (int nc = 0; nc < 4; ++nc) {
                const short8 bfr = *(const short8*)&sK[nc * 16 + n16][c * 32 + quad * 8];
                cf[nc] = __builtin_amdgcn_mfma_f32_16x16x32_bf16(a, bfr, cf[nc], 0, 0, 0);
            }
        }
        __builtin_amdgcn_s_setprio(0);

#pragma unroll
        for (int nc = 0; nc < 4; ++nc) {
            const int mvi = mp[k0 + nc * 16 + n16];
            // lane holds col (nc*16+n16), rows quad*4+{0..3} in regs
            float m0 = mvi ? __expf(cf[nc][0]) * linv[0] : 0.f;
            float m1 = mvi ? __expf(cf[nc][1]) * linv[1] : 0.f;
            float m2 = mvi ? __expf(cf[nc][2]) * linv[2] : 0.f;
            float m3 = mvi ? __expf(cf[nc][3]) * linv[3] : 0.f;
            // 4x4 in-register transpose across lanes (bits 0,1 of lane id):
            // stage 1: lane^1 / reg-bit0
            float s1_0 = __shfl_xor(m1, 1, 64);
            float s1_1 = __shfl_xor(m0, 1, 64);
            float s1_2 = __shfl_xor(m3, 1, 64);
            float s1_3 = __shfl_xor(m2, 1, 64);
            float n0 = (t4 & 1) ? s1_0 : m0;
            float n1 = (t4 & 1) ? m1 : s1_1;
            float n2 = (t4 & 1) ? s1_2 : m2;
            float n3 = (t4 & 1) ? m3 : s1_3;
            // stage 2: lane^2 / reg-bit1
            float s2_0 = __shfl_xor(n2, 2, 64);
            float s2_1 = __shfl_xor(n3, 2, 64);
            float s2_2 = __shfl_xor(n0, 2, 64);
            float s2_3 = __shfl_xor(n1, 2, 64);
            float4v w;
            w[0] = (t4 & 2) ? s2_0 : n0;
            w[1] = (t4 & 2) ? s2_1 : n1;
            w[2] = (t4 & 2) ? n2 : s2_2;
            w[3] = (t4 & 2) ? n3 : s2_3;
            // lane now holds row (quad*4+t4), cols k0+nc*16+g4*4 .. +3
            *(float4v*)&attn[abase + (size_t)(quad * 4 + t4) * S + k0 + nc * 16 + g4 * 4] = w;
        }
    }
}

// ---------------------------------------------------------------------------
extern "C" void kernel_launch(void* const* d_in, const int* in_sizes, int n_in,
                              void* d_out, int out_size, void* d_ws, size_t ws_size,
                              hipStream_t stream) {
    const float* q    = (const float*)d_in[0];
    const float* k    = (const float*)d_in[1];
    const float* v    = (const float*)d_in[2];
    const int*   mask = (const int*)d_in[3];
    // workspace: [0,8MB) K-bf16 row-major, [8MB,16MB) Vt bf16
    unsigned short* kbf = (unsigned short*)d_ws;
    unsigned short* vt  = kbf + (size_t)BH * S * D;
    float* out = (float*)d_out;

    cvt_kernel<<<dim3(1024), dim3(256), 0, stream>>>(k, kbf);
    vt_kernel<<<dim3(BH * (S / 64)), dim3(256), 0, stream>>>(v, vt);
    attn_kernel<<<dim3(BH * (S / QT)), dim3(256), 0, stream>>>(q, kbf, mask, vt, out);
}